// Round 1
// baseline (261.572 us; speedup 1.0000x reference)
//
#include <hip/hip_runtime.h>
#include <math.h>

#define NEGV -1e30f

constexpr int Bc = 256;   // batch
constexpr int Tc = 256;   // time
constexpr int Cc = 512;   // classes (blank = Cc-1)
constexpr int Lc = 64;    // max label length
constexpr int Sc = 2 * Lc + 1;  // 129 extended-label states

__global__ void zero_out_k(float* out) {
    if (threadIdx.x == 0 && blockIdx.x == 0) out[0] = 0.f;
}

// One wave per (b,t): logsumexp over C=512 classes.
// 64 lanes x 2 float4 = 512 floats, butterfly shuffle reduce.
__global__ __launch_bounds__(256) void denom_k(const float* __restrict__ logits,
                                               float* __restrict__ denom) {
    int gtid = blockIdx.x * 256 + threadIdx.x;
    int wid  = gtid >> 6;      // global wave id == b*Tc + t, grid sized exactly
    int lane = gtid & 63;

    const float4* r4 = (const float4*)(logits + (size_t)wid * Cc);
    float4 x0 = r4[lane];
    float4 x1 = r4[lane + 64];

    float m = fmaxf(fmaxf(fmaxf(x0.x, x0.y), fmaxf(x0.z, x0.w)),
                    fmaxf(fmaxf(x1.x, x1.y), fmaxf(x1.z, x1.w)));
#pragma unroll
    for (int o = 32; o; o >>= 1) m = fmaxf(m, __shfl_xor(m, o, 64));

    float sm = __expf(x0.x - m) + __expf(x0.y - m) + __expf(x0.z - m) + __expf(x0.w - m)
             + __expf(x1.x - m) + __expf(x1.y - m) + __expf(x1.z - m) + __expf(x1.w - m);
#pragma unroll
    for (int o = 32; o; o >>= 1) sm += __shfl_xor(sm, o, 64);

    if (lane == 0) denom[wid] = m + __logf(sm);
}

// One block per batch element, thread s handles extended-label state s.
// Alpha double-buffered in LDS; 1 barrier per timestep; emission gathered
// from logits (L3-resident) with one-deep prefetch.
__global__ __launch_bounds__(192) void ctc_fwd_k(const float* __restrict__ logits,
                                                 const int* __restrict__ labels,
                                                 const int* __restrict__ lab_len,
                                                 const int* __restrict__ log_len,
                                                 const float* __restrict__ denom,
                                                 float* __restrict__ out) {
    int b = blockIdx.x;
    int s = threadIdx.x;

    __shared__ float alpha[2][Sc + 3];
    __shared__ float dsh[Tc];
    __shared__ float fin[2];

    // stage denom row for this batch into LDS (1 KB)
    for (int i = threadIdx.x; i < Tc; i += 192) dsh[i] = denom[b * Tc + i];

    const bool active = (s < Sc);
    const int  ll  = log_len[b];
    const int  end = 2 * lab_len[b];

    int  y = Cc - 1;      // blank for even s
    bool skip = false;
    if (active && (s & 1)) {
        y = labels[b * Lc + (s >> 1)];
        if (s >= 3) skip = (y != labels[b * Lc + (s >> 1) - 1]);
    }

    const float* lb = logits + (size_t)b * Tc * Cc;

    __syncthreads();   // dsh ready

    // t = 0
    if (active) {
        float a = (s <= 1) ? (lb[y] - dsh[0]) : NEGV;
        alpha[0][s] = a;
        if (ll == 1) {
            if (s == end)     fin[0] = a;
            if (s == end - 1) fin[1] = a;
        }
    }
    // prefetch raw logit for t = 1
    float rcur = active ? lb[(size_t)Cc + y] : 0.f;
    int pb = 0;
    __syncthreads();

    for (int t = 1; t < Tc; ++t) {
        float rnext = (active && (t + 1 < Tc)) ? lb[(size_t)(t + 1) * Cc + y] : 0.f;
        if (active) {
            float a0 = alpha[pb][s];
            float a1 = (s >= 1) ? alpha[pb][s - 1] : NEGV;
            float a2 = skip ? alpha[pb][s - 2] : NEGV;
            float m  = fmaxf(fmaxf(a0, a1), a2);
            float sm = __expf(a0 - m) + __expf(a1 - m) + __expf(a2 - m);
            float na = m + __logf(sm) + (rcur - dsh[t]);
            alpha[pb ^ 1][s] = na;
            if (t == ll - 1) {
                if (s == end)          fin[0] = na;
                else if (s == end - 1) fin[1] = na;
            }
        }
        rcur = rnext;
        pb ^= 1;
        __syncthreads();
    }

    if (threadIdx.x == 0) {
        float m   = fmaxf(fin[0], fin[1]);
        float nll = -(m + __logf(__expf(fin[0] - m) + __expf(fin[1] - m)));
        atomicAdd(out, nll * (1.0f / Bc));
    }
}

extern "C" void kernel_launch(void* const* d_in, const int* in_sizes, int n_in,
                              void* d_out, int out_size, void* d_ws, size_t ws_size,
                              hipStream_t stream) {
    const float* logits  = (const float*)d_in[0];
    const int*   labels  = (const int*)d_in[1];
    const int*   lab_len = (const int*)d_in[2];
    const int*   log_len = (const int*)d_in[3];
    float* out   = (float*)d_out;
    float* denom = (float*)d_ws;   // Bc*Tc floats = 256 KB

    hipLaunchKernelGGL(zero_out_k, dim3(1), dim3(64), 0, stream, out);
    hipLaunchKernelGGL(denom_k, dim3(Bc * Tc / 4), dim3(256), 0, stream, logits, denom);
    hipLaunchKernelGGL(ctc_fwd_k, dim3(Bc), dim3(192), 0, stream,
                       logits, labels, lab_len, log_len, denom, out);
}